// Round 10
// baseline (15.464 us; speedup 1.0000x reference)
//
#include <hip/hip_runtime.h>

#define B_ROWS 16384
#define D_DIM  256
#define C_CLS  4096
#define CPB    8      // classes per block
#define MAXM   64     // member slots per class (mean cnt = 4, Poisson tail ~0)
#define NBLK   (C_CLS / CPB)   // 512
#define CLAMP_LO 1e-12f
#define CLAMP_HI 1e12f

__device__ __forceinline__ float wave_reduce_sum(float v) {
    for (int o = 32; o > 0; o >>= 1) v += __shfl_xor(v, o, 64);
    return v;
}
__device__ __forceinline__ int wave_reduce_min(int v) {
    for (int o = 32; o > 0; o >>= 1) v = min(v, __shfl_xor(v, o, 64));
    return v;
}

// K1: 512 blocks x 1024 threads; block owns classes [C0, C0+8).
// Phase A: every block scans ALL 16K labels (64 KB, L2-broadcast-hot),
// building its classes' member lists in LDS; global min label = first class.
// Phase B: 2 waves per class gather member x-rows with a 4-deep load pipeline
// (4 independent VMEM loads per round -> one HBM latency per round, not four).
// Block reduces its 8 class contributions in LDS -> one partial per block.
__global__ __launch_bounds__(1024, 8) void k_class(const float* __restrict__ x,
                                                   const float* __restrict__ centers,
                                                   const int* __restrict__ labels,
                                                   float* __restrict__ partial) {
    const int t = threadIdx.x;
    const int lane = t & 63;
    const int wv = t >> 6;            // 0..15
    const int C0 = blockIdx.x * CPB;

    __shared__ int cnt[CPB];
    __shared__ int members[CPB][MAXM];
    __shared__ int minRed[16];
    __shared__ float shc[CPB];
    if (t < CPB) cnt[t] = 0;
    __syncthreads();

    // ---- Phase A: label scan ----
    const int4* __restrict__ L4 = reinterpret_cast<const int4*>(labels);
    int myMin = 0x7FFFFFFF;
    #pragma unroll
    for (int j = 0; j < 4; ++j) {
        const int4 lv = L4[t + 1024 * j];
        const int r = 4 * (t + 1024 * j);
        myMin = min(myMin, min(min(lv.x, lv.y), min(lv.z, lv.w)));
        int d;
        d = lv.x - C0; if ((unsigned)d < CPB) { const int p_ = atomicAdd(&cnt[d], 1); if (p_ < MAXM) members[d][p_] = r + 0; }
        d = lv.y - C0; if ((unsigned)d < CPB) { const int p_ = atomicAdd(&cnt[d], 1); if (p_ < MAXM) members[d][p_] = r + 1; }
        d = lv.z - C0; if ((unsigned)d < CPB) { const int p_ = atomicAdd(&cnt[d], 1); if (p_ < MAXM) members[d][p_] = r + 2; }
        d = lv.w - C0; if ((unsigned)d < CPB) { const int p_ = atomicAdd(&cnt[d], 1); if (p_ < MAXM) members[d][p_] = r + 3; }
    }
    myMin = wave_reduce_min(myMin);
    if (lane == 0) minRed[wv] = myMin;
    __syncthreads();

    // ---- Phase B: per-class gather + contribution ----
    const int cls = wv >> 1;          // 0..7
    const int half = wv & 1;          // 0,1
    const int c = C0 + cls;
    const int cn = cnt[cls];

    int fc = minRed[0];
    #pragma unroll
    for (int i = 1; i < 16; ++i) fc = min(fc, minRed[i]);
    const bool isFirst = (c == fc);

    const float4* __restrict__ X = reinterpret_cast<const float4*>(x);

    // centers row issued early (independent of the member->x chain)
    float4 cv = make_float4(0.f, 0.f, 0.f, 0.f);
    if (half == 0)
        cv = reinterpret_cast<const float4*>(centers)[(size_t)c * (D_DIM / 4) + lane];

    float sx = 0.0f, sy = 0.0f, sz = 0.0f, sw = 0.0f, q = 0.0f;
    // 4-deep pipelined gather: rows half, half+2, ... ; 4 per round per wave.
    for (int base = half; base < cn; base += 8) {
        const int i1 = base + 2, i2 = base + 4, i3 = base + 6;
        const int b0 = members[cls][base];
        const int b1 = (i1 < cn) ? members[cls][i1] : b0;  // dup -> L1 hit
        const int b2 = (i2 < cn) ? members[cls][i2] : b0;
        const int b3 = (i3 < cn) ? members[cls][i3] : b0;
        const float k1 = (i1 < cn) ? 1.0f : 0.0f;
        const float k2 = (i2 < cn) ? 1.0f : 0.0f;
        const float k3 = (i3 < cn) ? 1.0f : 0.0f;
        const float4 v0 = X[(size_t)b0 * (D_DIM / 4) + lane];
        const float4 v1 = X[(size_t)b1 * (D_DIM / 4) + lane];
        const float4 v2 = X[(size_t)b2 * (D_DIM / 4) + lane];
        const float4 v3 = X[(size_t)b3 * (D_DIM / 4) + lane];
        sx += v0.x + k1 * v1.x + k2 * v2.x + k3 * v3.x;
        sy += v0.y + k1 * v1.y + k2 * v2.y + k3 * v3.y;
        sz += v0.z + k1 * v1.z + k2 * v2.z + k3 * v3.z;
        sw += v0.w + k1 * v1.w + k2 * v2.w + k3 * v3.w;
        q += (v0.x * v0.x + v0.y * v0.y + v0.z * v0.z + v0.w * v0.w)
           + k1 * (v1.x * v1.x + v1.y * v1.y + v1.z * v1.z + v1.w * v1.w)
           + k2 * (v2.x * v2.x + v2.y * v2.y + v2.z * v2.z + v2.w * v2.w)
           + k3 * (v3.x * v3.x + v3.y * v3.y + v3.z * v3.z + v3.w * v3.w);
    }

    __shared__ float4 sh_s[CPB][2][64];
    __shared__ float sh_q[CPB][2];
    sh_s[cls][half][lane] = make_float4(sx, sy, sz, sw);
    const float qq = wave_reduce_sum(q);
    if (lane == 0) sh_q[cls][half] = qq;
    __syncthreads();

    if (half == 0) {
        if (cn == 0) {
            if (lane == 0) shc[cls] = (float)B_ROWS * CLAMP_LO;  // denom = 1
        } else {
            const float4 p0 = sh_s[cls][0][lane], p1 = sh_s[cls][1][lane];
            const float t0 = p0.x + p1.x;
            const float t1 = p0.y + p1.y;
            const float t2 = p0.z + p1.z;
            const float t3 = p0.w + p1.w;
            const float Q = sh_q[cls][0] + sh_q[cls][1];

            const float inv = 1.0f / (float)cn;
            float n0 = t0 * inv, n1 = t1 * inv, n2 = t2 * inv, n3 = t3 * inv;
            if (!isFirst) {
                n0 = 0.5f * cv.x + 0.5f * n0;
                n1 = 0.5f * cv.y + 0.5f * n1;
                n2 = 0.5f * cv.z + 0.5f * n2;
                n3 = 0.5f * cv.w + 0.5f * n3;
            }
            const float A1 = wave_reduce_sum(t0 * n0 + t1 * n1 + t2 * n2 + t3 * n3);
            const float A2 = wave_reduce_sum(n0 * n0 + n1 * n1 + n2 * n2 + n3 * n3);
            if (lane == 0) {
                float S = Q - 2.0f * A1 + (float)cn * A2;
                // per-row clamp only binds where the closed form gives exactly
                // 0 (singleton first class) -> class-level clamp is exact
                S = fminf(fmaxf(S, CLAMP_LO), CLAMP_HI);
                shc[cls] = (S + (float)(B_ROWS - cn) * CLAMP_LO) / (float)cn;
            }
        }
    }
    __syncthreads();
    if (t == 0) {
        float p = 0.0f;
        #pragma unroll
        for (int i = 0; i < CPB; ++i) p += shc[i];
        partial[blockIdx.x] = p;
    }
}

// K2: sum 512 block partials, scale. (Separate dispatch = free device-wide
// barrier; fused variants pay same-address atomic/fence serialization: R4.)
__global__ void __launch_bounds__(256) k_final(const float* __restrict__ partial,
                                               float* __restrict__ out) {
    const int t = threadIdx.x;
    float acc = 0.0f;
    if (t < NBLK / 4) {
        const float4 v = reinterpret_cast<const float4*>(partial)[t];
        acc = v.x + v.y + v.z + v.w;
    }
    acc = wave_reduce_sum(acc);
    __shared__ float red[4];
    if ((t & 63) == 0) red[t >> 6] = acc;
    __syncthreads();
    if (t == 0) {
        const float total = red[0] + red[1];   // only waves 0,1 carry data
        out[0] = total / (float)((size_t)C_CLS * D_DIM);
    }
}

extern "C" void kernel_launch(void* const* d_in, const int* in_sizes, int n_in,
                              void* d_out, int out_size, void* d_ws, size_t ws_size,
                              hipStream_t stream) {
    const float* x       = (const float*)d_in[0];
    const float* centers = (const float*)d_in[1];
    const int*   labels  = (const int*)d_in[2];
    float* out = (float*)d_out;

    float* partial = (float*)d_ws;   // 2 KB

    k_class<<<NBLK, 1024, 0, stream>>>(x, centers, labels, partial);
    k_final<<<1, 256, 0, stream>>>(partial, out);
}

// Round 11
// 12.908 us; speedup vs baseline: 1.1980x; 1.1980x over previous
//
#include <hip/hip_runtime.h>

#define B_ROWS 16384
#define D_DIM  256
#define C_CLS  4096
#define CPB    8      // classes per block
#define MAXM   64     // member slots per class (mean cnt = 4, Poisson tail ~0)
#define NBLK   (C_CLS / CPB)   // 512
#define CLAMP_LO 1e-12f
#define CLAMP_HI 1e12f

__device__ __forceinline__ float wave_reduce_sum(float v) {
    for (int o = 32; o > 0; o >>= 1) v += __shfl_xor(v, o, 64);
    return v;
}
__device__ __forceinline__ int wave_reduce_min(int v) {
    for (int o = 32; o > 0; o >>= 1) v = min(v, __shfl_xor(v, o, 64));
    return v;
}

// K1: 512 blocks x 1024 threads; block owns classes [C0, C0+8).
// Phase A: every block scans ALL 16K labels (64 KB, L2-broadcast-hot),
// building its classes' member lists in LDS; global min label = first class.
// Phase B: 2 waves per class gather member x-rows (lane = 4 dims as float4,
// 1-ahead LDS index prefetch — R10's deeper pipeline regressed: dup loads
// doubled VMEM for the common cnt~4 class). Block folds its 8 class
// contributions into one partial.
__global__ void __launch_bounds__(1024) k_class(const float* __restrict__ x,
                                                const float* __restrict__ centers,
                                                const int* __restrict__ labels,
                                                float* __restrict__ partial) {
    const int t = threadIdx.x;
    const int lane = t & 63;
    const int wv = t >> 6;            // 0..15
    const int C0 = blockIdx.x * CPB;

    __shared__ int cnt[CPB];
    __shared__ int members[CPB][MAXM];
    __shared__ int minRed[16];
    __shared__ float shc[CPB];
    if (t < CPB) cnt[t] = 0;
    __syncthreads();

    // ---- Phase A: label scan ----
    const int4* __restrict__ L4 = reinterpret_cast<const int4*>(labels);
    int myMin = 0x7FFFFFFF;
    #pragma unroll
    for (int j = 0; j < 4; ++j) {
        const int4 lv = L4[t + 1024 * j];
        const int r = 4 * (t + 1024 * j);
        myMin = min(myMin, min(min(lv.x, lv.y), min(lv.z, lv.w)));
        int d;
        d = lv.x - C0; if ((unsigned)d < CPB) { const int p_ = atomicAdd(&cnt[d], 1); if (p_ < MAXM) members[d][p_] = r + 0; }
        d = lv.y - C0; if ((unsigned)d < CPB) { const int p_ = atomicAdd(&cnt[d], 1); if (p_ < MAXM) members[d][p_] = r + 1; }
        d = lv.z - C0; if ((unsigned)d < CPB) { const int p_ = atomicAdd(&cnt[d], 1); if (p_ < MAXM) members[d][p_] = r + 2; }
        d = lv.w - C0; if ((unsigned)d < CPB) { const int p_ = atomicAdd(&cnt[d], 1); if (p_ < MAXM) members[d][p_] = r + 3; }
    }
    myMin = wave_reduce_min(myMin);
    if (lane == 0) minRed[wv] = myMin;
    __syncthreads();

    // ---- Phase B: per-class gather + contribution ----
    const int cls = wv >> 1;          // 0..7
    const int half = wv & 1;          // 0,1
    const int c = C0 + cls;
    const int cn = cnt[cls];

    int fc = minRed[0];
    #pragma unroll
    for (int i = 1; i < 16; ++i) fc = min(fc, minRed[i]);
    const bool isFirst = (c == fc);

    const float4* __restrict__ X = reinterpret_cast<const float4*>(x);

    // centers row issued early (independent of the member->x chain)
    float4 cv = make_float4(0.f, 0.f, 0.f, 0.f);
    if (half == 0)
        cv = reinterpret_cast<const float4*>(centers)[(size_t)c * (D_DIM / 4) + lane];

    float sx = 0.0f, sy = 0.0f, sz = 0.0f, sw = 0.0f, q = 0.0f;
    int i = half;
    int b = (i < cn) ? members[cls][i] : 0;
    while (i < cn) {
        const int inext = i + 2;
        const int bn = (inext < cn) ? members[cls][inext] : 0;
        const float4 v = X[(size_t)b * (D_DIM / 4) + lane];
        sx += v.x; sy += v.y; sz += v.z; sw += v.w;
        q += v.x * v.x + v.y * v.y + v.z * v.z + v.w * v.w;
        b = bn; i = inext;
    }

    __shared__ float4 sh_s[CPB][2][64];
    __shared__ float sh_q[CPB][2];
    sh_s[cls][half][lane] = make_float4(sx, sy, sz, sw);
    const float qq = wave_reduce_sum(q);
    if (lane == 0) sh_q[cls][half] = qq;
    __syncthreads();

    if (half == 0) {
        if (cn == 0) {
            if (lane == 0) shc[cls] = (float)B_ROWS * CLAMP_LO;  // denom = 1
        } else {
            const float4 p0 = sh_s[cls][0][lane], p1 = sh_s[cls][1][lane];
            const float t0 = p0.x + p1.x;
            const float t1 = p0.y + p1.y;
            const float t2 = p0.z + p1.z;
            const float t3 = p0.w + p1.w;
            const float Q = sh_q[cls][0] + sh_q[cls][1];

            const float inv = 1.0f / (float)cn;
            float n0 = t0 * inv, n1 = t1 * inv, n2 = t2 * inv, n3 = t3 * inv;
            if (!isFirst) {
                n0 = 0.5f * cv.x + 0.5f * n0;
                n1 = 0.5f * cv.y + 0.5f * n1;
                n2 = 0.5f * cv.z + 0.5f * n2;
                n3 = 0.5f * cv.w + 0.5f * n3;
            }
            const float A1 = wave_reduce_sum(t0 * n0 + t1 * n1 + t2 * n2 + t3 * n3);
            const float A2 = wave_reduce_sum(n0 * n0 + n1 * n1 + n2 * n2 + n3 * n3);
            if (lane == 0) {
                float S = Q - 2.0f * A1 + (float)cn * A2;
                // per-row clamp only binds where the closed form gives exactly
                // 0 (singleton first class) -> class-level clamp is exact
                S = fminf(fmaxf(S, CLAMP_LO), CLAMP_HI);
                shc[cls] = (S + (float)(B_ROWS - cn) * CLAMP_LO) / (float)cn;
            }
        }
    }
    __syncthreads();
    if (t == 0) {
        float p = 0.0f;
        #pragma unroll
        for (int i2 = 0; i2 < CPB; ++i2) p += shc[i2];
        partial[blockIdx.x] = p;
    }
}

// K2: sum 512 block partials, scale. (Separate dispatch = free device-wide
// barrier; fused variants pay same-address atomic/fence serialization: R4.)
__global__ void __launch_bounds__(256) k_final(const float* __restrict__ partial,
                                               float* __restrict__ out) {
    const int t = threadIdx.x;
    float acc = 0.0f;
    if (t < NBLK / 4) {
        const float4 v = reinterpret_cast<const float4*>(partial)[t];
        acc = v.x + v.y + v.z + v.w;
    }
    acc = wave_reduce_sum(acc);
    __shared__ float red[4];
    if ((t & 63) == 0) red[t >> 6] = acc;
    __syncthreads();
    if (t == 0) {
        const float total = red[0] + red[1];   // only waves 0,1 carry data
        out[0] = total / (float)((size_t)C_CLS * D_DIM);
    }
}

extern "C" void kernel_launch(void* const* d_in, const int* in_sizes, int n_in,
                              void* d_out, int out_size, void* d_ws, size_t ws_size,
                              hipStream_t stream) {
    const float* x       = (const float*)d_in[0];
    const float* centers = (const float*)d_in[1];
    const int*   labels  = (const int*)d_in[2];
    float* out = (float*)d_out;

    float* partial = (float*)d_ws;   // 2 KB

    k_class<<<NBLK, 1024, 0, stream>>>(x, centers, labels, partial);
    k_final<<<1, 256, 0, stream>>>(partial, out);
}